// Round 4
// baseline (385.369 us; speedup 1.0000x reference)
//
#include <hip/hip_runtime.h>

#define BB 16
#define CC 128
#define HH 64
#define WW 64
#define NG 8
#define WPB 147456       // 128*128*9 weights per sample
#define PLANE 4096       // 64*64
#define GROUP_N 65536.f  // 16 ch * 4096 px

typedef __attribute__((ext_vector_type(8))) short short8;
typedef __attribute__((ext_vector_type(4))) float floatx4;
typedef __attribute__((ext_vector_type(4))) unsigned short ushortx4;

__device__ __forceinline__ unsigned short f2bf(float f) {
    unsigned u = __builtin_bit_cast(unsigned, f);
    return (unsigned short)((u + 0x7fffu + ((u >> 16) & 1u)) >> 16);
}
__device__ __forceinline__ float bf2f(unsigned short h) {
    unsigned u = ((unsigned)h) << 16;
    return __builtin_bit_cast(float, u);
}

// ---------- transpose x (fp32 NCHW) -> Xt0[b][icc][y][x][ic32] bf16 ----------
__global__ __launch_bounds__(256)
void transpose_in(const float* __restrict__ x, unsigned short* __restrict__ xt)
{
    int blk = blockIdx.x;                 // 4096 = 16b * 4icc * 64y
    int b = blk >> 8, icc = (blk >> 6) & 3, y = blk & 63;
    int xi = threadIdx.x & 63, vg = threadIdx.x >> 6;   // vg 0..3 -> 8 channels
    const float* src = x + (((size_t)(b * CC + icc * 32 + vg * 8)) * HH + y) * WW + xi;
    short8 o;
#pragma unroll
    for (int e = 0; e < 8; ++e) o[e] = (short)f2bf(src[(size_t)e * PLANE]);
    unsigned short* dst = xt + (((size_t)(b * 4 + icc) * PLANE) + y * WW + xi) * 32 + vg * 8;
    *(short8*)dst = o;
}

// ---------- hypernet GEMM via MFMA: P[which][b][n] bf16 ----------------------
// A = z (16 batch x 128 k, bf16, loaded once per wave). Per 16-col tile:
// B-frag = hw[k][n..n+15] (32 k per mfma), 8 strided dword loads each
// (4 x 64B contiguous segments per instr). D[m=batch][n=col].
// grid 1152 x 4 waves, 4 tiles/wave = 18432 tiles = 294912 cols (both heads).
__global__ __launch_bounds__(256)
void gemm_mfma(const float* __restrict__ z,
               const float* __restrict__ h1w, const float* __restrict__ h1b,
               const float* __restrict__ h2w, const float* __restrict__ h2b,
               unsigned short* __restrict__ P)
{
    const int tid = threadIdx.x;
    const int lane = tid & 63;
    const int l = lane & 15, q = lane >> 4;
    const int gw = blockIdx.x * 4 + (tid >> 6);   // global wave id, 0..4607

    // A-fragments: z[m=l][k=kc*32+q*8+j], j=0..7 -> bf16 short8 per kc
    short8 a[4];
#pragma unroll
    for (int kc = 0; kc < 4; ++kc) {
        const float* zp = z + l * 128 + kc * 32 + q * 8;
        float4 z0 = *(const float4*)zp;
        float4 z1 = *(const float4*)(zp + 4);
        short8 o;
        o[0] = (short)f2bf(z0.x); o[1] = (short)f2bf(z0.y);
        o[2] = (short)f2bf(z0.z); o[3] = (short)f2bf(z0.w);
        o[4] = (short)f2bf(z1.x); o[5] = (short)f2bf(z1.y);
        o[6] = (short)f2bf(z1.z); o[7] = (short)f2bf(z1.w);
        a[kc] = o;
    }

#pragma unroll
    for (int it = 0; it < 4; ++it) {
        const int t = gw * 4 + it;                 // tile id, 0..18431
        const int which = (t >= 9216) ? 1 : 0;
        const int n = (t - which * 9216) * 16;
        const float* __restrict__ hw = which ? h2w : h1w;
        const float* __restrict__ hb = which ? h2b : h1b;

        floatx4 acc = (floatx4)0.f;
#pragma unroll
        for (int kc = 0; kc < 4; ++kc) {
            float hv[8];
#pragma unroll
            for (int j = 0; j < 8; ++j)
                hv[j] = hw[(size_t)(kc * 32 + q * 8 + j) * WPB + n + l];
            short8 bfr;
#pragma unroll
            for (int j = 0; j < 8; ++j) bfr[j] = (short)f2bf(hv[j]);
            acc = __builtin_amdgcn_mfma_f32_16x16x32_bf16(a[kc], bfr, acc, 0, 0, 0);
        }

        const float bias = hb[n + l];
        unsigned short* pw = P + (size_t)which * 2359296;
#pragma unroll
        for (int r = 0; r < 4; ++r) {
            int batch = q * 4 + r;
            pw[(size_t)batch * WPB + n + l] = f2bf(acc[r] + bias);
        }
    }
}

// ---------- repack plain P[b][n] -> MFMA A-fragment layout -------------------
// Wf[b][icc][tap][frag][lane][j], oc=frag*16+(lane&15), ic=icc*32+(lane>>4)*8+j
__global__ __launch_bounds__(256)
void repack(const unsigned short* __restrict__ P,
            unsigned short* __restrict__ wf1, unsigned short* __restrict__ wf2)
{
    int gid = blockIdx.x * 256 + threadIdx.x;   // 65536 = 2 * 16b*4icc*8frag*64lane
    int which = gid >> 15, g = gid & 32767;
    int lane = g & 63, frag = (g >> 6) & 7, icc = (g >> 9) & 3, b = g >> 11;

    const unsigned short* src = P + (size_t)which * 2359296 + (size_t)b * WPB
        + (frag * 16 + (lane & 15)) * 1152 + (icc * 32 + (lane >> 4) * 8) * 9;
    unsigned short buf[72];
#pragma unroll
    for (int i = 0; i < 9; ++i)
        *(short8*)(buf + i * 8) = *(const short8*)(src + i * 8);  // 16B-aligned

    unsigned short* wf = which ? wf2 : wf1;
#pragma unroll
    for (int tap = 0; tap < 9; ++tap) {
        short8 o;
#pragma unroll
        for (int j = 0; j < 8; ++j) o[j] = (short)buf[j * 9 + tap];
        size_t off = ((((size_t)(b * 4 + icc) * 9 + tap) * 8 + frag) * 64 + lane) * 8;
        *(short8*)(wf + off) = o;   // contiguous 1KB per wave per tap
    }
}

// ---------- MFMA conv: 9 tap-shifted GEMMs over ic-chunks --------------------
// block = 4 waves: wave(i=m-half, j=row). Block tile: 128 oc x 2 rows x 64 px.
// MODE 0: write bf16 Xt layout + stats ; MODE 1: write fp32 NCHW + stats
template <int MODE>
__global__ __launch_bounds__(256, 2)
void conv_mfma(const unsigned short* __restrict__ xt,
               const unsigned short* __restrict__ wf,
               unsigned short* __restrict__ yt, float* __restrict__ ynchw,
               float* __restrict__ stats)
{
    const int blk = blockIdx.x;          // 512 = 16b * 32tiles
    const int b = blk >> 5, tile = blk & 31;
    const int tid = threadIdx.x;
    const int w = tid >> 6, lane = tid & 63;
    const int i = w >> 1, j = w & 1;     // m-half, row-within-tile
    const int q = lane >> 4, n16 = lane & 15;
    const int y = tile * 2 + j;

    floatx4 acc[4][4];
#pragma unroll
    for (int mf = 0; mf < 4; ++mf)
#pragma unroll
        for (int nf = 0; nf < 4; ++nf) acc[mf][nf] = (floatx4)0.f;

    const unsigned short* xtb_b = xt + (size_t)b * 4 * PLANE * 32;
    const unsigned short* wf_b  = wf + (size_t)b * WPB;

    for (int icc = 0; icc < 4; ++icc) {
        const unsigned short* xtb = xtb_b + (size_t)icc * PLANE * 32;
        const unsigned short* wfc = wf_b + (size_t)icc * 36864;   // 9*8*64*8
#pragma unroll
        for (int tap = 0; tap < 9; ++tap) {
            const int dy = tap / 3 - 1, dx = tap % 3 - 1;
            const int yy = y + dy;
            if ((unsigned)yy >= (unsigned)HH) continue;   // wave-uniform

            short8 a[4], bbf[4];
#pragma unroll
            for (int mf = 0; mf < 4; ++mf)
                a[mf] = *(const short8*)(wfc + (((size_t)(tap * 8 + i * 4 + mf)) * 64 + lane) * 8);
#pragma unroll
            for (int nf = 0; nf < 4; ++nf) {
                int xx = nf * 16 + n16 + dx;
                if ((unsigned)xx < (unsigned)WW)
                    bbf[nf] = *(const short8*)(xtb + ((size_t)(yy * WW + xx)) * 32 + q * 8);
                else
                    bbf[nf] = (short8)0;
            }
#pragma unroll
            for (int mf = 0; mf < 4; ++mf)
#pragma unroll
                for (int nf = 0; nf < 4; ++nf)
                    acc[mf][nf] = __builtin_amdgcn_mfma_f32_16x16x32_bf16(
                        a[mf], bbf[nf], acc[mf][nf], 0, 0, 0);
        }
    }

    // ---- epilogue: store + fused GN stats (group g == i*4 + mf) ----
#pragma unroll
    for (int mf = 0; mf < 4; ++mf) {
        float s1 = 0.f, s2 = 0.f;
#pragma unroll
        for (int nf = 0; nf < 4; ++nf) {
#pragma unroll
            for (int r = 0; r < 4; ++r) {
                float v = acc[mf][nf][r];
                s1 += v; s2 += v * v;
            }
            const int xx = nf * 16 + n16;
            if (MODE == 0) {
                const int icc1 = i * 2 + (mf >> 1);
                const int v0 = (mf & 1) * 16 + q * 4;
                unsigned short* p = yt + (((size_t)(b * 4 + icc1) * PLANE) + y * WW + xx) * 32 + v0;
                ushortx4 u;
                u.x = f2bf(acc[mf][nf][0]); u.y = f2bf(acc[mf][nf][1]);
                u.z = f2bf(acc[mf][nf][2]); u.w = f2bf(acc[mf][nf][3]);
                *(ushortx4*)p = u;
            } else {
#pragma unroll
                for (int r = 0; r < 4; ++r) {
                    int oc = i * 64 + mf * 16 + q * 4 + r;
                    ynchw[(((size_t)(b * CC + oc)) * HH + y) * WW + xx] = acc[mf][nf][r];
                }
            }
        }
#pragma unroll
        for (int off = 32; off > 0; off >>= 1) {
            s1 += __shfl_down(s1, off, 64);
            s2 += __shfl_down(s2, off, 64);
        }
        if (lane == 0) {
            int g = i * 4 + mf;
            atomicAdd(&stats[(b * NG + g) * 2 + 0], s1);
            atomicAdd(&stats[(b * NG + g) * 2 + 1], s2);
        }
    }
}

// ---------- in-place GN1 + ReLU over bf16 Xt layout --------------------------
__global__ __launch_bounds__(256)
void norm_relu_bf16(unsigned short* __restrict__ yt, const float* __restrict__ stats,
                    const float* __restrict__ gamma, const float* __restrict__ beta)
{
    int idx8 = blockIdx.x * 256 + threadIdx.x;      // 1,048,576 groups of 8
    int t = idx8 >> 2;
    int bicc = t >> 12;
    int b = bicc >> 2, icc = bicc & 3;
    int cb = icc * 32 + (idx8 & 3) * 8;             // 8 consecutive channels, one group
    int g = cb >> 4;
    float sum = stats[(b * NG + g) * 2 + 0];
    float ssq = stats[(b * NG + g) * 2 + 1];
    float mean = sum * (1.f / GROUP_N);
    float var  = ssq * (1.f / GROUP_N) - mean * mean;
    float inv  = rsqrtf(var + 1e-5f);

    short8 d = *(short8*)(yt + (size_t)idx8 * 8);
    short8 o;
#pragma unroll
    for (int e = 0; e < 8; ++e) {
        float s = gamma[cb + e] * inv;
        float tt = beta[cb + e] - mean * s;
        float v = bf2f((unsigned short)d[e]);
        o[e] = (short)f2bf(fmaxf(v * s + tt, 0.f));
    }
    *(short8*)(yt + (size_t)idx8 * 8) = o;
}

// ---------- final: out = relu(GN2(y2) + x), in place over d_out --------------
__global__ __launch_bounds__(256)
void gn_add_relu(float* __restrict__ y2, const float* __restrict__ x,
                 const float* __restrict__ stats, const float* __restrict__ gamma,
                 const float* __restrict__ beta)
{
    const int bc = blockIdx.x;
    const int b = bc >> 7, c = bc & 127;
    const int g = c >> 4;
    float sum  = stats[(b * NG + g) * 2 + 0];
    float ssq  = stats[(b * NG + g) * 2 + 1];
    float mean = sum * (1.f / GROUP_N);
    float var  = ssq * (1.f / GROUP_N) - mean * mean;
    float inv  = rsqrtf(var + 1e-5f);
    float s = gamma[c] * inv;
    float t = beta[c] - mean * s;

    size_t base = (size_t)bc * PLANE;
    float4* yp = (float4*)(y2 + base);
    const float4* xp = (const float4*)(x + base);
    for (int i = threadIdx.x; i < PLANE / 4; i += 256) {
        float4 v = yp[i], xv = xp[i];
        v.x = fmaxf(v.x * s + t + xv.x, 0.f);
        v.y = fmaxf(v.y * s + t + xv.y, 0.f);
        v.z = fmaxf(v.z * s + t + xv.z, 0.f);
        v.w = fmaxf(v.w * s + t + xv.w, 0.f);
        yp[i] = v;
    }
}

extern "C" void kernel_launch(void* const* d_in, const int* in_sizes, int n_in,
                              void* d_out, int out_size, void* d_ws, size_t ws_size,
                              hipStream_t stream)
{
    const float* x   = (const float*)d_in[0];
    const float* z   = (const float*)d_in[1];
    const float* h1w = (const float*)d_in[2];
    const float* h1b = (const float*)d_in[3];
    const float* h2w = (const float*)d_in[4];
    const float* h2b = (const float*)d_in[5];
    const float* g1  = (const float*)d_in[6];
    const float* b1  = (const float*)d_in[7];
    const float* g2  = (const float*)d_in[8];
    const float* b2  = (const float*)d_in[9];
    float* out = (float*)d_out;

    // ws: stats(2048B) | Wf1(4.71MB) | Wf2(4.71MB) | Xt0(16.8MB) | Xt1(16.8MB)
    // P (plain bf16 GEMM out, 9.4MB) aliases Xt1 — lifetime ends at repack,
    // before conv1 overwrites Xt1.
    float* stats1 = (float*)d_ws;
    float* stats2 = stats1 + 256;
    unsigned short* wf1 = (unsigned short*)((char*)d_ws + 2048);
    unsigned short* wf2 = wf1 + 2359296;
    unsigned short* xt0 = wf2 + 2359296;
    unsigned short* xt1 = xt0 + 8388608;
    unsigned short* P   = xt1;   // alias

    hipMemsetAsync(d_ws, 0, 2048, stream);

    // x -> Xt0 (bf16, ic-contiguous chunks)
    transpose_in<<<4096, 256, 0, stream>>>(x, xt0);

    // both hypernet heads via MFMA: stream 151MB once -> plain P, then repack
    gemm_mfma<<<1152, 256, 0, stream>>>(z, h1w, h1b, h2w, h2b, P);
    repack<<<256, 256, 0, stream>>>(P, wf1, wf2);

    // conv1 -> Xt1 raw + stats1 (overwrites P after repack is done)
    conv_mfma<0><<<512, 256, 0, stream>>>(xt0, wf1, xt1, nullptr, stats1);

    // GN1 + ReLU in place on Xt1
    norm_relu_bf16<<<4096, 256, 0, stream>>>(xt1, stats1, g1, b1);

    // conv2 -> d_out raw fp32 + stats2
    conv_mfma<1><<<512, 256, 0, stream>>>(xt1, wf2, nullptr, out, stats2);

    // out = relu(GN2(out) + x)
    gn_add_relu<<<2048, 256, 0, stream>>>(out, x, stats2, g2, b2);
}

// Round 5
// 374.417 us; speedup vs baseline: 1.0292x; 1.0292x over previous
//
#include <hip/hip_runtime.h>

#define BB 16
#define CC 128
#define HH 64
#define WW 64
#define NG 8
#define WPB 147456       // 128*128*9 weights per sample
#define PLANE 4096       // 64*64
#define GROUP_N 65536.f  // 16 ch * 4096 px

typedef __attribute__((ext_vector_type(8))) short short8;
typedef __attribute__((ext_vector_type(4))) float floatx4;
typedef __attribute__((ext_vector_type(4))) unsigned short ushortx4;

__device__ __forceinline__ unsigned short f2bf(float f) {
    unsigned u = __builtin_bit_cast(unsigned, f);
    return (unsigned short)((u + 0x7fffu + ((u >> 16) & 1u)) >> 16);
}
__device__ __forceinline__ float bf2f(unsigned short h) {
    unsigned u = ((unsigned)h) << 16;
    return __builtin_bit_cast(float, u);
}

// ---------- fused: hypernet GEMM (blocks 0..287) + input transpose (rest) ----
// GEMM: wave owns a contiguous 256-col n-window; lane loads hw[k][n0+lane*4]
// as float4 -> every wave-instr is a dense 1KB segment (coalescing sweet spot).
// z staged in LDS, broadcast ds_reads; fp32 accum; P[which][b][n] bf16 out.
// Transpose: x (fp32 NCHW) -> Xt0[b][icc][y][x][ic32] bf16.
__global__ __launch_bounds__(256)
void prep(const float* __restrict__ x, const float* __restrict__ z,
          const float* __restrict__ h1w, const float* __restrict__ h1b,
          const float* __restrict__ h2w, const float* __restrict__ h2b,
          unsigned short* __restrict__ xt, unsigned short* __restrict__ P)
{
    __shared__ float zs[2048];
    const int tid = threadIdx.x;

    if (blockIdx.x < 288) {
        // ---------------- GEMM branch ----------------
        for (int i = tid; i < 2048; i += 256) zs[i] = z[i];
        __syncthreads();

        const int gwin  = blockIdx.x * 4 + (tid >> 6);   // 0..1151 wave windows
        const int which = (gwin >= 576) ? 1 : 0;
        const int win   = gwin - which * 576;
        const float* __restrict__ hw = which ? h2w : h1w;
        const float* __restrict__ hb = which ? h2b : h1b;
        const int n = win * 256 + (tid & 63) * 4;

        float acc[16][4];
#pragma unroll
        for (int b = 0; b < 16; ++b)
#pragma unroll
            for (int c = 0; c < 4; ++c) acc[b][c] = 0.f;

        for (int k0 = 0; k0 < 128; k0 += 8) {
            float4 hv[8];
#pragma unroll
            for (int u = 0; u < 8; ++u)
                hv[u] = *(const float4*)(hw + (size_t)(k0 + u) * WPB + n);
#pragma unroll
            for (int b = 0; b < 16; ++b) {
                const float* zp = &zs[b * 128 + k0];
#pragma unroll
                for (int u = 0; u < 8; ++u) {
                    float zv = zp[u];
                    acc[b][0] = fmaf(zv, hv[u].x, acc[b][0]);
                    acc[b][1] = fmaf(zv, hv[u].y, acc[b][1]);
                    acc[b][2] = fmaf(zv, hv[u].z, acc[b][2]);
                    acc[b][3] = fmaf(zv, hv[u].w, acc[b][3]);
                }
            }
        }

        const float4 bias = *(const float4*)(hb + n);
        unsigned short* pw = P + (size_t)which * 2359296;
#pragma unroll
        for (int b = 0; b < 16; ++b) {
            ushortx4 u4;
            u4.x = f2bf(acc[b][0] + bias.x);
            u4.y = f2bf(acc[b][1] + bias.y);
            u4.z = f2bf(acc[b][2] + bias.z);
            u4.w = f2bf(acc[b][3] + bias.w);
            *(ushortx4*)(pw + (size_t)b * WPB + n) = u4;   // 512B/wave contiguous
        }
    } else {
        // ---------------- transpose branch ----------------
        int blk = blockIdx.x - 288;           // 4096 = 16b * 4icc * 64y
        int b = blk >> 8, icc = (blk >> 6) & 3, y = blk & 63;
        int xi = tid & 63, vg = tid >> 6;     // vg 0..3 -> 8 channels
        const float* src = x + (((size_t)(b * CC + icc * 32 + vg * 8)) * HH + y) * WW + xi;
        short8 o;
#pragma unroll
        for (int e = 0; e < 8; ++e) o[e] = (short)f2bf(src[(size_t)e * PLANE]);
        unsigned short* dst = xt + (((size_t)(b * 4 + icc) * PLANE) + y * WW + xi) * 32 + vg * 8;
        *(short8*)dst = o;
    }
}

// ---------- repack plain P[b][n] -> MFMA A-fragment layout (+zero stats) -----
// Wf[b][icc][tap][frag][lane][j], oc=frag*16+(lane&15), ic=icc*32+(lane>>4)*8+j
__global__ __launch_bounds__(256)
void repack(const unsigned short* __restrict__ P,
            unsigned short* __restrict__ wf1, unsigned short* __restrict__ wf2,
            float* __restrict__ stats)
{
    if (blockIdx.x == 0) {                    // fold stats1+stats2 zeroing here
        stats[threadIdx.x] = 0.f;
        stats[threadIdx.x + 256] = 0.f;
    }

    int gid = blockIdx.x * 256 + threadIdx.x;   // 65536 = 2 * 16b*4icc*8frag*64lane
    int which = gid >> 15, g = gid & 32767;
    int lane = g & 63, frag = (g >> 6) & 7, icc = (g >> 9) & 3, b = g >> 11;

    const unsigned short* src = P + (size_t)which * 2359296 + (size_t)b * WPB
        + (frag * 16 + (lane & 15)) * 1152 + (icc * 32 + (lane >> 4) * 8) * 9;
    unsigned short buf[72];
#pragma unroll
    for (int i = 0; i < 9; ++i)
        *(short8*)(buf + i * 8) = *(const short8*)(src + i * 8);  // 16B-aligned

    unsigned short* wf = which ? wf2 : wf1;
#pragma unroll
    for (int tap = 0; tap < 9; ++tap) {
        short8 o;
#pragma unroll
        for (int j = 0; j < 8; ++j) o[j] = (short)buf[j * 9 + tap];
        size_t off = ((((size_t)(b * 4 + icc) * 9 + tap) * 8 + frag) * 64 + lane) * 8;
        *(short8*)(wf + off) = o;   // contiguous 1KB per wave per tap
    }
}

// ---------- MFMA conv: 9 tap-shifted GEMMs over ic-chunks --------------------
// block = 4 waves: wave(i=m-half, j=row). Block tile: 128 oc x 2 rows x 64 px.
// MODE 0: write bf16 Xt layout + stats ; MODE 1: write fp32 NCHW + stats
template <int MODE>
__global__ __launch_bounds__(256, 2)
void conv_mfma(const unsigned short* __restrict__ xt,
               const unsigned short* __restrict__ wf,
               unsigned short* __restrict__ yt, float* __restrict__ ynchw,
               float* __restrict__ stats)
{
    const int blk = blockIdx.x;          // 512 = 16b * 32tiles
    const int b = blk >> 5, tile = blk & 31;
    const int tid = threadIdx.x;
    const int w = tid >> 6, lane = tid & 63;
    const int i = w >> 1, j = w & 1;     // m-half, row-within-tile
    const int q = lane >> 4, n16 = lane & 15;
    const int y = tile * 2 + j;

    floatx4 acc[4][4];
#pragma unroll
    for (int mf = 0; mf < 4; ++mf)
#pragma unroll
        for (int nf = 0; nf < 4; ++nf) acc[mf][nf] = (floatx4)0.f;

    const unsigned short* xtb_b = xt + (size_t)b * 4 * PLANE * 32;
    const unsigned short* wf_b  = wf + (size_t)b * WPB;

    for (int icc = 0; icc < 4; ++icc) {
        const unsigned short* xtb = xtb_b + (size_t)icc * PLANE * 32;
        const unsigned short* wfc = wf_b + (size_t)icc * 36864;   // 9*8*64*8
#pragma unroll
        for (int tap = 0; tap < 9; ++tap) {
            const int dy = tap / 3 - 1, dx = tap % 3 - 1;
            const int yy = y + dy;
            if ((unsigned)yy >= (unsigned)HH) continue;   // wave-uniform

            short8 a[4], bbf[4];
#pragma unroll
            for (int mf = 0; mf < 4; ++mf)
                a[mf] = *(const short8*)(wfc + (((size_t)(tap * 8 + i * 4 + mf)) * 64 + lane) * 8);
#pragma unroll
            for (int nf = 0; nf < 4; ++nf) {
                int xx = nf * 16 + n16 + dx;
                if ((unsigned)xx < (unsigned)WW)
                    bbf[nf] = *(const short8*)(xtb + ((size_t)(yy * WW + xx)) * 32 + q * 8);
                else
                    bbf[nf] = (short8)0;
            }
#pragma unroll
            for (int mf = 0; mf < 4; ++mf)
#pragma unroll
                for (int nf = 0; nf < 4; ++nf)
                    acc[mf][nf] = __builtin_amdgcn_mfma_f32_16x16x32_bf16(
                        a[mf], bbf[nf], acc[mf][nf], 0, 0, 0);
        }
    }

    // ---- epilogue: store + fused GN stats (group g == i*4 + mf) ----
#pragma unroll
    for (int mf = 0; mf < 4; ++mf) {
        float s1 = 0.f, s2 = 0.f;
#pragma unroll
        for (int nf = 0; nf < 4; ++nf) {
#pragma unroll
            for (int r = 0; r < 4; ++r) {
                float v = acc[mf][nf][r];
                s1 += v; s2 += v * v;
            }
            const int xx = nf * 16 + n16;
            if (MODE == 0) {
                const int icc1 = i * 2 + (mf >> 1);
                const int v0 = (mf & 1) * 16 + q * 4;
                unsigned short* p = yt + (((size_t)(b * 4 + icc1) * PLANE) + y * WW + xx) * 32 + v0;
                ushortx4 u;
                u.x = f2bf(acc[mf][nf][0]); u.y = f2bf(acc[mf][nf][1]);
                u.z = f2bf(acc[mf][nf][2]); u.w = f2bf(acc[mf][nf][3]);
                *(ushortx4*)p = u;
            } else {
#pragma unroll
                for (int r = 0; r < 4; ++r) {
                    int oc = i * 64 + mf * 16 + q * 4 + r;
                    ynchw[(((size_t)(b * CC + oc)) * HH + y) * WW + xx] = acc[mf][nf][r];
                }
            }
        }
#pragma unroll
        for (int off = 32; off > 0; off >>= 1) {
            s1 += __shfl_down(s1, off, 64);
            s2 += __shfl_down(s2, off, 64);
        }
        if (lane == 0) {
            int g = i * 4 + mf;
            atomicAdd(&stats[(b * NG + g) * 2 + 0], s1);
            atomicAdd(&stats[(b * NG + g) * 2 + 1], s2);
        }
    }
}

// ---------- in-place GN1 + ReLU over bf16 Xt layout --------------------------
__global__ __launch_bounds__(256)
void norm_relu_bf16(unsigned short* __restrict__ yt, const float* __restrict__ stats,
                    const float* __restrict__ gamma, const float* __restrict__ beta)
{
    int idx8 = blockIdx.x * 256 + threadIdx.x;      // 1,048,576 groups of 8
    int t = idx8 >> 2;
    int bicc = t >> 12;
    int b = bicc >> 2, icc = bicc & 3;
    int cb = icc * 32 + (idx8 & 3) * 8;             // 8 consecutive channels, one group
    int g = cb >> 4;
    float sum = stats[(b * NG + g) * 2 + 0];
    float ssq = stats[(b * NG + g) * 2 + 1];
    float mean = sum * (1.f / GROUP_N);
    float var  = ssq * (1.f / GROUP_N) - mean * mean;
    float inv  = rsqrtf(var + 1e-5f);

    short8 d = *(short8*)(yt + (size_t)idx8 * 8);
    short8 o;
#pragma unroll
    for (int e = 0; e < 8; ++e) {
        float s = gamma[cb + e] * inv;
        float tt = beta[cb + e] - mean * s;
        float v = bf2f((unsigned short)d[e]);
        o[e] = (short)f2bf(fmaxf(v * s + tt, 0.f));
    }
    *(short8*)(yt + (size_t)idx8 * 8) = o;
}

// ---------- final: out = relu(GN2(y2) + x), in place over d_out --------------
__global__ __launch_bounds__(256)
void gn_add_relu(float* __restrict__ y2, const float* __restrict__ x,
                 const float* __restrict__ stats, const float* __restrict__ gamma,
                 const float* __restrict__ beta)
{
    const int bc = blockIdx.x;
    const int b = bc >> 7, c = bc & 127;
    const int g = c >> 4;
    float sum  = stats[(b * NG + g) * 2 + 0];
    float ssq  = stats[(b * NG + g) * 2 + 1];
    float mean = sum * (1.f / GROUP_N);
    float var  = ssq * (1.f / GROUP_N) - mean * mean;
    float inv  = rsqrtf(var + 1e-5f);
    float s = gamma[c] * inv;
    float t = beta[c] - mean * s;

    size_t base = (size_t)bc * PLANE;
    float4* yp = (float4*)(y2 + base);
    const float4* xp = (const float4*)(x + base);
    for (int i = threadIdx.x; i < PLANE / 4; i += 256) {
        float4 v = yp[i], xv = xp[i];
        v.x = fmaxf(v.x * s + t + xv.x, 0.f);
        v.y = fmaxf(v.y * s + t + xv.y, 0.f);
        v.z = fmaxf(v.z * s + t + xv.z, 0.f);
        v.w = fmaxf(v.w * s + t + xv.w, 0.f);
        yp[i] = v;
    }
}

extern "C" void kernel_launch(void* const* d_in, const int* in_sizes, int n_in,
                              void* d_out, int out_size, void* d_ws, size_t ws_size,
                              hipStream_t stream)
{
    const float* x   = (const float*)d_in[0];
    const float* z   = (const float*)d_in[1];
    const float* h1w = (const float*)d_in[2];
    const float* h1b = (const float*)d_in[3];
    const float* h2w = (const float*)d_in[4];
    const float* h2b = (const float*)d_in[5];
    const float* g1  = (const float*)d_in[6];
    const float* b1  = (const float*)d_in[7];
    const float* g2  = (const float*)d_in[8];
    const float* b2  = (const float*)d_in[9];
    float* out = (float*)d_out;

    // ws: stats(2048B) | Wf1(4.71MB) | Wf2(4.71MB) | Xt0(16.8MB) | Xt1(16.8MB)
    // P (plain bf16 GEMM out, 9.4MB) aliases Xt1 — lifetime ends at repack,
    // before conv1 overwrites Xt1.
    float* stats1 = (float*)d_ws;
    float* stats2 = stats1 + 256;
    unsigned short* wf1 = (unsigned short*)((char*)d_ws + 2048);
    unsigned short* wf2 = wf1 + 2359296;
    unsigned short* xt0 = wf2 + 2359296;
    unsigned short* xt1 = xt0 + 8388608;
    unsigned short* P   = xt1;   // alias

    // fused: hypernet GEMM (288 blocks, launched first -> co-resident) + transpose
    prep<<<288 + 4096, 256, 0, stream>>>(x, z, h1w, h1b, h2w, h2b, xt0, P);

    // P -> fragment layouts; also zeroes stats1/stats2
    repack<<<256, 256, 0, stream>>>(P, wf1, wf2, stats1);

    // conv1 -> Xt1 raw + stats1 (overwrites P after repack is done)
    conv_mfma<0><<<512, 256, 0, stream>>>(xt0, wf1, xt1, nullptr, stats1);

    // GN1 + ReLU in place on Xt1
    norm_relu_bf16<<<4096, 256, 0, stream>>>(xt1, stats1, g1, b1);

    // conv2 -> d_out raw fp32 + stats2
    conv_mfma<1><<<512, 256, 0, stream>>>(xt1, wf2, nullptr, out, stats2);

    // out = relu(GN2(out) + x)
    gn_add_relu<<<2048, 256, 0, stream>>>(out, x, stats2, g2, b2);
}